// Round 3
// baseline (6364.165 us; speedup 1.0000x reference)
//
#include <hip/hip_runtime.h>
#include <hip/hip_cooperative_groups.h>
#include <math.h>

namespace cg = cooperative_groups;

#define BB 64
#define TT 32
#define II 512
#define HH 1024
#define OO 512
#define NN 1024
#define MM 64
#define EPSF 1e-8f

// layouts:
//  hT4  [k4 0..255][b 0..63][4]   (transposed h, float4 per (k4,b))
//  xiT4 [k4 0..127][b 0..63][4]
//  YT   [row 0..3071][b 0..63]    (Whh·h + bhh)
//  memT [b][m 0..63][n 0..1023]
// GEMV row space: 0..3071 = Whh rows, 3072..3583 = Who rows

struct P {
  const float *Wk_r,*bk_r,*Wb_r,*bb_r,*Wg_r,*bg_r,*Ws_r,*bs_r,*Wga_r,*bga_r;
  const float *Wk_w,*bk_w,*Wb_w,*bb_w,*Wg_w,*bg_w,*Ws_w,*bs_w,*Wga_w,*bga_w;
  const float *We,*be,*Wa,*ba,*W_r2i,*b_r2i,*Wih,*bih,*Whh,*bhh,*Who,*bho;
  const float *x, *mem0;
  float *outs, *wr, *ww, *memOut, *h;      // outputs (h = final-h region)
  float *hT4, *YT, *xiT4, *W_r2iT, *memT;  // workspace (~17.3 MB)
};

__device__ __forceinline__ float sigmf(float x){ return 1.f/(1.f+expf(-x)); }
__device__ __forceinline__ float splusf(float x){ return fmaxf(x,0.f) + log1pf(expf(-fabsf(x))); }
__device__ __forceinline__ float4 ld4(const float* p){ return *reinterpret_cast<const float4*>(p); }
__device__ __forceinline__ void st4(float* p, float4 v){ *reinterpret_cast<float4*>(p) = v; }
__device__ __forceinline__ float wredsum(float v){
  #pragma unroll
  for (int o = 32; o; o >>= 1) v += __shfl_xor(v, o);
  return v;
}
__device__ __forceinline__ float wredmax(float v){
  #pragma unroll
  for (int o = 32; o; o >>= 1) v = fmaxf(v, __shfl_xor(v, o));
  return v;
}
#define ACC4(A, s, v) { A.x = fmaf(s, v.x, A.x); A.y = fmaf(s, v.y, A.y); A.z = fmaf(s, v.z, A.z); A.w = fmaf(s, v.w, A.w); }
#define SQ4(A, v)     { A.x = fmaf(v.x, v.x, A.x); A.y = fmaf(v.y, v.y, A.y); A.z = fmaf(v.z, v.z, A.z); A.w = fmaf(v.w, v.w, A.w); }
#define DOT4(a, w, v) a = fmaf(w.x, v.x, fmaf(w.y, v.y, fmaf(w.z, v.z, fmaf(w.w, v.w, a))))

// ---------------- per-head softmax/shift/sharpen (block = one b) ----------------
__device__ void process_head(const P& p, float* smem, int head, float4 sim, float4 qq,
                             int b, int tid, int wv, int lane) {
  float* scal = smem + 1344;
  float* red  = smem + 1360;
  float* wg_s = smem + 1616;
  float* wsm  = (head ? smem + 3664 : smem + 2640);   // wB : wA
  float* wbuf = (head ? p.ww : p.wr) + (size_t)b*NN;
  const int n4 = tid*4;
  const float beta = scal[head*4+0], g = scal[head*4+1];
  const float gam = scal[head*4+2], kn = scal[head*4+3];
  const float s0 = scal[8+head*3+0], s1 = scal[8+head*3+1], s2 = scal[8+head*3+2];
  float4 pp;
  pp.x = beta*sim.x/(kn*sqrtf(qq.x)+EPSF);
  pp.y = beta*sim.y/(kn*sqrtf(qq.y)+EPSF);
  pp.z = beta*sim.z/(kn*sqrtf(qq.z)+EPSF);
  pp.w = beta*sim.w/(kn*sqrtf(qq.w)+EPSF);
  float mx = wredmax(fmaxf(fmaxf(pp.x,pp.y), fmaxf(pp.z,pp.w)));
  if (lane == 0) red[wv] = mx;
  __syncthreads();
  mx = fmaxf(fmaxf(red[0],red[1]), fmaxf(red[2],red[3]));
  pp.x = expf(pp.x-mx); pp.y = expf(pp.y-mx); pp.z = expf(pp.z-mx); pp.w = expf(pp.w-mx);
  float sm = wredsum(pp.x+pp.y+pp.z+pp.w);
  if (lane == 0) red[4+wv] = sm;
  __syncthreads();
  const float inv = 1.f/(red[4]+red[5]+red[6]+red[7]);
  float4 wp = ld4(wbuf + n4);
  float4 wg;
  wg.x = g*(pp.x*inv) + (1.f-g)*wp.x;
  wg.y = g*(pp.y*inv) + (1.f-g)*wp.y;
  wg.z = g*(pp.z*inv) + (1.f-g)*wp.z;
  wg.w = g*(pp.w*inv) + (1.f-g)*wp.w;
  st4(&wg_s[n4], wg);
  __syncthreads();
  float wm1 = wg_s[(n4 + NN - 1) & (NN-1)];
  float wp4 = wg_s[(n4 + 4) & (NN-1)];
  float4 wt, w;
  wt.x = s0*wm1  + s1*wg.x + s2*wg.y;
  wt.y = s0*wg.x + s1*wg.y + s2*wg.z;
  wt.z = s0*wg.y + s1*wg.z + s2*wg.w;
  wt.w = s0*wg.z + s1*wg.w + s2*wp4;
  w.x = powf(wt.x + 1e-12f, gam);
  w.y = powf(wt.y + 1e-12f, gam);
  w.z = powf(wt.z + 1e-12f, gam);
  w.w = powf(wt.w + 1e-12f, gam);
  float ps = wredsum(w.x+w.y+w.z+w.w);
  if (lane == 0) red[wv] = ps;
  __syncthreads();
  const float invw = 1.f/((red[0]+red[1]+red[2]+red[3]) + EPSF);
  w.x *= invw; w.y *= invw; w.z *= invw; w.w *= invw;
  st4(wbuf + n4, w);
  st4(&wsm[n4], w);
  __syncthreads();
}

// ---------------- phase A, blocks 0..63: full per-b NTM chain ----------------
__device__ void bchain(const P& p, float* smem, int t, int b) {
  const int tid = threadIdx.x;
  const int wv = __builtin_amdgcn_readfirstlane(tid >> 6);
  const int lane = tid & 63;
  float* h_s  = smem;          // 1024
  float* kr_s = smem + 1024;   // 64
  float* kw_s = smem + 1088;
  float* e_s  = smem + 1152;
  float* a_s  = smem + 1216;
  float* r_s  = smem + 1280;
  float* scal = smem + 1344;   // 16
  float* wA   = smem + 2640;   // 1024
  float* wB   = smem + 3664;   // 1024

  ((float4*)h_s)[tid] = ld4(p.h + (size_t)b*HH + tid*4);
  __syncthreads();

  // ---- gates: 268 wave-rows, weights from L2/LLC ----
  for (int r = wv; r < 268; r += 4) {
    const float* wrow; float bias; int act; float* dst;
    if (r < 140) {
      const int head = (r >= 70);
      const int q = r - head*70;
      if (q < 64)      { wrow = (head?p.Wk_w:p.Wk_r) + (size_t)q*HH; bias = (head?p.bk_w:p.bk_r)[q]; act=0; dst = (head?kw_s:kr_s)+q; }
      else if (q==64)  { wrow = head?p.Wb_w:p.Wb_r; bias=(head?p.bb_w:p.bb_r)[0]; act=1; dst=&scal[head*4+0]; }
      else if (q==65)  { wrow = head?p.Wg_w:p.Wg_r; bias=(head?p.bg_w:p.bg_r)[0]; act=2; dst=&scal[head*4+1]; }
      else if (q<69)   { const int i2=q-66; wrow=(head?p.Ws_w:p.Ws_r)+(size_t)i2*HH; bias=(head?p.bs_w:p.bs_r)[i2]; act=5; dst=&scal[8+head*3+i2]; }
      else             { wrow = head?p.Wga_w:p.Wga_r; bias=(head?p.bga_w:p.bga_r)[0]; act=4; dst=&scal[head*4+2]; }
    } else if (r < 204) { const int m=r-140; wrow=p.We+(size_t)m*HH; bias=p.be[m]; act=2; dst=&e_s[m]; }
    else                { const int m=r-204; wrow=p.Wa+(size_t)m*HH; bias=p.ba[m]; act=0; dst=&a_s[m]; }
    float acc = 0.f;
    #pragma unroll
    for (int c = 0; c < 4; ++c) {
      float4 w = ld4(wrow + c*256 + lane*4);
      float4 hh = ld4(&h_s[c*256 + lane*4]);
      acc += w.x*hh.x + w.y*hh.y + w.z*hh.z + w.w*hh.w;
    }
    acc = wredsum(acc);
    if (lane == 0) {
      float v = acc + bias;
      if (act==0) v = tanhf(v);
      else if (act==1) v = splusf(v);
      else if (act==2) v = sigmf(v);
      else if (act==4) v = 1.f + splusf(v);
      *dst = v;
    }
  }
  __syncthreads();
  if (wv == 0) { float v = kr_s[lane]; float q = wredsum(v*v); if (lane==0) scal[3] = sqrtf(q); }
  else if (wv == 1) { float v = kw_s[lane]; float q = wredsum(v*v); if (lane==0) scal[7] = sqrtf(q); }
  if (tid < 2) {
    float* sv = &scal[8 + tid*3];
    float a0=sv[0], a1=sv[1], a2=sv[2];
    float mxs = fmaxf(a0, fmaxf(a1,a2));
    float e0=expf(a0-mxs), e1=expf(a1-mxs), e2=expf(a2-mxs);
    float inv = 1.f/(e0+e1+e2);
    sv[0]=e0*inv; sv[1]=e1*inv; sv[2]=e2*inv;
  }
  __syncthreads();

  // ---- single combined mem pass: sim_r, sim_w, ||mem_n||^2 ----
  const int n4 = tid*4;
  float* mb = p.memT + (size_t)b*MM*NN;
  float4 sr = {0,0,0,0}, sw = {0,0,0,0}, qq = {0,0,0,0};
  #pragma unroll 4
  for (int m = 0; m < MM; m += 4) {
    float4 kr4 = ld4(&kr_s[m]);
    float4 kw4 = ld4(&kw_s[m]);
    float4 v0 = ld4(mb + (size_t)(m+0)*NN + n4);
    float4 v1 = ld4(mb + (size_t)(m+1)*NN + n4);
    float4 v2 = ld4(mb + (size_t)(m+2)*NN + n4);
    float4 v3 = ld4(mb + (size_t)(m+3)*NN + n4);
    ACC4(sr, kr4.x, v0) ACC4(sr, kr4.y, v1) ACC4(sr, kr4.z, v2) ACC4(sr, kr4.w, v3)
    ACC4(sw, kw4.x, v0) ACC4(sw, kw4.y, v1) ACC4(sw, kw4.z, v2) ACC4(sw, kw4.w, v3)
    SQ4(qq, v0) SQ4(qq, v1) SQ4(qq, v2) SQ4(qq, v3)
  }

  process_head(p, smem, 0, sr, qq, b, tid, wv, lane);
  process_head(p, smem, 1, sw, qq, b, tid, wv, lane);

  // ---- combined read + erase/add pass ----
  float4 wAr[4], wBr[4];
  #pragma unroll
  for (int c = 0; c < 4; ++c) { wAr[c] = ld4(&wA[c*256 + lane*4]); wBr[c] = ld4(&wB[c*256 + lane*4]); }
  for (int i = 0; i < 16; ++i) {
    const int m = wv*16 + i;
    const float em = e_s[m], am = a_s[m];
    float* rowp = mb + (size_t)m*NN;
    float racc = 0.f;
    #pragma unroll
    for (int c = 0; c < 4; ++c) {
      float4 v = ld4(rowp + c*256 + lane*4);
      racc += wAr[c].x*v.x + wAr[c].y*v.y + wAr[c].z*v.z + wAr[c].w*v.w;
      float4 nv;
      nv.x = fmaf(wBr[c].x, fmaf(-em, v.x, am), v.x);
      nv.y = fmaf(wBr[c].y, fmaf(-em, v.y, am), v.y);
      nv.z = fmaf(wBr[c].z, fmaf(-em, v.z, am), v.z);
      nv.w = fmaf(wBr[c].w, fmaf(-em, v.w, am), v.w);
      st4(rowp + c*256 + lane*4, nv);
    }
    racc = wredsum(racc);
    if (lane == 0) r_s[m] = racc;
  }
  __syncthreads();

  // ---- rinxi -> xiT4 ----
  if (tid < 128) {
    const int i0 = tid*4;
    float4 acc = ld4(p.b_r2i + i0);
    #pragma unroll 4
    for (int m = 0; m < MM; ++m) {
      float rm = r_s[m];
      float4 w = ld4(p.W_r2iT + (size_t)m*II + i0);
      ACC4(acc, rm, w)
    }
    float4 xv = ld4(p.x + ((size_t)b*TT + t)*II + i0);
    float4 xi;
    xi.x = fmaxf(xv.x + fmaxf(acc.x, 0.f), 0.f);
    xi.y = fmaxf(xv.y + fmaxf(acc.y, 0.f), 0.f);
    xi.z = fmaxf(xv.z + fmaxf(acc.z, 0.f), 0.f);
    xi.w = fmaxf(xv.w + fmaxf(acc.w, 0.f), 0.f);
    st4(p.xiT4 + ((size_t)tid*64 + b)*4, xi);
  }
}

// ---------------- phase A GEMV: rows of [Whh;Who] · h, lanes = b ----------------
// weights read at wave-uniform addresses from ORIGINAL layout (row-contiguous in k)
template<int RPW>
__device__ void a_matmul(const P& p, int t, int row0) {
  const int tid = threadIdx.x;
  const int wv = __builtin_amdgcn_readfirstlane(tid >> 6);
  const int lane = tid & 63;
  const int r0 = row0 + wv*RPW;
  float acc[RPW];
  const float* wrows[RPW];
  #pragma unroll
  for (int j = 0; j < RPW; ++j) {
    acc[j] = 0.f;
    const int gr = r0 + j;
    wrows[j] = (gr < 3072) ? p.Whh + (size_t)gr*HH
             : (gr < 3584) ? p.Who + (size_t)(gr-3072)*HH
             : p.Whh;                               // safe dummy for pad rows
  }
  const float* hp = p.hT4 + lane*4;
  #pragma unroll 2
  for (int k4 = 0; k4 < 256; ++k4) {
    float4 hv = ld4(hp + (size_t)k4*256);
    #pragma unroll
    for (int j = 0; j < RPW; ++j) {
      float4 w = ld4(wrows[j] + k4*4);
      DOT4(acc[j], w, hv);
    }
  }
  #pragma unroll
  for (int j = 0; j < RPW; ++j) {
    const int gr = r0 + j;
    if (gr < 3072) {
      p.YT[(size_t)gr*64 + lane] = acc[j] + p.bhh[gr];
    } else if (gr < 3584) {
      if (t >= 1) {
        const int o = gr - 3072;
        p.outs[((size_t)lane*TT + (t-1))*OO + o] = sigmf(acc[j] + p.bho[o]);
      }
    }
  }
}

// ---------------- phase B, all 256 blocks: gi GEMV (4 cols) + fused GRU ----------------
__device__ void b_gigru(const P& p, float* smem, int blk) {
  const int tid = threadIdx.x;
  const int wv = __builtin_amdgcn_readfirstlane(tid >> 6);
  const int lane = tid & 63;
  const int j0 = blk * 4;
  float* gi_s = smem;   // 12*64
  float acc[3];
  const float* wrows[3];
  #pragma unroll
  for (int q = 0; q < 3; ++q) {
    const int rr = wv*3 + q;                       // rr = gate*4 + localcol
    const int row = (rr>>2)*1024 + j0 + (rr&3);
    acc[q] = p.bih[row];
    wrows[q] = p.Wih + (size_t)row*II;
  }
  const float* xp = p.xiT4 + lane*4;
  #pragma unroll 2
  for (int k4 = 0; k4 < 128; ++k4) {
    float4 xv = ld4(xp + (size_t)k4*256);
    #pragma unroll
    for (int q = 0; q < 3; ++q) {
      float4 w = ld4(wrows[q] + k4*4);
      DOT4(acc[q], w, xv);
    }
  }
  #pragma unroll
  for (int q = 0; q < 3; ++q) gi_s[(wv*3+q)*64 + lane] = acc[q];
  __syncthreads();
  // one thread per (j, b)
  const int jl = tid >> 6;        // 0..3
  const int b  = tid & 63;
  const int j  = j0 + jl;
  float gir = gi_s[(0 + jl)*64 + b];
  float giz = gi_s[(4 + jl)*64 + b];
  float gin = gi_s[(8 + jl)*64 + b];
  float ghr = p.YT[(size_t)j*64 + b];
  float ghz = p.YT[(size_t)(1024+j)*64 + b];
  float ghn = p.YT[(size_t)(2048+j)*64 + b];
  float hold = p.hT4[((size_t)(j>>2)*64 + b)*4 + (j&3)];
  float rr_ = sigmf(gir + ghr);
  float zz  = sigmf(giz + ghz);
  float nn_ = tanhf(gin + rr_*ghn);
  float hn = (1.f-zz)*nn_ + zz*hold;
  p.h[(size_t)b*HH + j] = hn;
  p.hT4[((size_t)(j>>2)*64 + b)*4 + (j&3)] = hn;
}

// ---------------- prologue / epilogue transposes ----------------
__device__ void memT_build(const P& p, float* smem, int b) {
  const int tid = threadIdx.x, wv = tid>>6, lane = tid&63;
  float* tile = smem;   // 64x65
  for (int nt = 0; nt < 16; ++nt) {
    const int n0 = nt*64;
    __syncthreads();
    #pragma unroll
    for (int i = 0; i < 16; ++i) {
      const int nn = (wv<<4) + i;
      tile[nn*65 + lane] = p.mem0[((size_t)b*NN + n0 + nn)*MM + lane];
    }
    __syncthreads();
    #pragma unroll
    for (int i = 0; i < 16; ++i) {
      const int m = (wv<<4) + i;
      p.memT[((size_t)b*MM + m)*NN + n0 + lane] = tile[lane*65 + m];
    }
  }
}

__device__ void memT_out(const P& p, float* smem, int b) {
  const int tid = threadIdx.x, wv = tid>>6, lane = tid&63;
  float* tile = smem;
  for (int nt = 0; nt < 16; ++nt) {
    const int n0 = nt*64;
    __syncthreads();
    #pragma unroll
    for (int i = 0; i < 16; ++i) {
      const int m = (wv<<4) + i;
      tile[lane*65 + m] = p.memT[((size_t)b*MM + m)*NN + n0 + lane];
    }
    __syncthreads();
    #pragma unroll
    for (int i = 0; i < 16; ++i) {
      const int nn = (wv<<4) + i;
      p.memOut[((size_t)b*NN + n0 + nn)*MM + lane] = tile[nn*65 + lane];
    }
  }
}

// ---------------- single persistent kernel ----------------
__global__ __launch_bounds__(256, 1) void ntm_all(P p) {
  __shared__ float smem[4800];
  cg::grid_group grid = cg::this_grid();
  const int blk = blockIdx.x;
  const int tid = threadIdx.x;

  // prologue: memT (0..63), W_r2iT (64..127), hT4 (128..191)
  if (blk < 64) {
    memT_build(p, smem, blk);
  } else if (blk < 128) {
    const int m = blk - 64;
    for (int ii = tid; ii < II; ii += 256)
      p.W_r2iT[(size_t)m*II + ii] = p.W_r2i[(size_t)ii*MM + m];
  } else if (blk < 192) {
    const int b = blk - 128;
    float4 v = ld4(p.h + (size_t)b*HH + tid*4);
    st4(p.hT4 + ((size_t)tid*64 + b)*4, v);
  }
  grid.sync();

  for (int t = 0; t < TT; ++t) {
    if (blk < 64) bchain(p, smem, t, blk);
    else a_matmul<5>(p, t, (blk-64)*20);           // 192 blocks x 4 waves x 5 = 3840 >= 3584
    grid.sync();
    b_gigru(p, smem, blk);                          // 256 blocks x 4 cols = 1024
    grid.sync();
  }

  // epilogue: final-step outputs + mem back-transpose
  if (blk < 16) a_matmul<8>(p, TT, 3072 + blk*32);  // 512 Who rows
  else if (blk < 80) memT_out(p, smem, blk - 16);
}

extern "C" void kernel_launch(void* const* d_in, const int* in_sizes, int n_in,
                              void* d_out, int out_size, void* d_ws, size_t ws_size,
                              hipStream_t stream) {
  const float* x    = (const float*)d_in[0];
  const float* h0   = (const float*)d_in[1];
  const float* wr0  = (const float*)d_in[2];
  const float* ww0  = (const float*)d_in[3];
  const float* mem0 = (const float*)d_in[4];
  P p;
  int i = 5;
  p.Wk_r  = (const float*)d_in[i++]; p.bk_r  = (const float*)d_in[i++];
  p.Wb_r  = (const float*)d_in[i++]; p.bb_r  = (const float*)d_in[i++];
  p.Wg_r  = (const float*)d_in[i++]; p.bg_r  = (const float*)d_in[i++];
  p.Ws_r  = (const float*)d_in[i++]; p.bs_r  = (const float*)d_in[i++];
  p.Wga_r = (const float*)d_in[i++]; p.bga_r = (const float*)d_in[i++];
  p.Wk_w  = (const float*)d_in[i++]; p.bk_w  = (const float*)d_in[i++];
  p.Wb_w  = (const float*)d_in[i++]; p.bb_w  = (const float*)d_in[i++];
  p.Wg_w  = (const float*)d_in[i++]; p.bg_w  = (const float*)d_in[i++];
  p.Ws_w  = (const float*)d_in[i++]; p.bs_w  = (const float*)d_in[i++];
  p.Wga_w = (const float*)d_in[i++]; p.bga_w = (const float*)d_in[i++];
  p.We    = (const float*)d_in[i++]; p.be    = (const float*)d_in[i++];
  p.Wa    = (const float*)d_in[i++]; p.ba    = (const float*)d_in[i++];
  p.W_r2i = (const float*)d_in[i++]; p.b_r2i = (const float*)d_in[i++];
  p.Wih   = (const float*)d_in[i++]; p.bih   = (const float*)d_in[i++];
  p.Whh   = (const float*)d_in[i++]; p.bhh   = (const float*)d_in[i++];
  p.Who   = (const float*)d_in[i++]; p.bho   = (const float*)d_in[i++];
  p.x = x; p.mem0 = mem0;

  float* out = (float*)d_out;
  p.outs   = out;                                  // (B,T,O)
  p.h      = out + (size_t)BB*TT*OO;               // (B,H) final h
  p.wr     = p.h + (size_t)BB*HH;                  // (B,N)
  p.ww     = p.wr + (size_t)BB*NN;                 // (B,N)
  p.memOut = p.ww + (size_t)BB*NN;                 // (B,N,M)

  float* ws = (float*)d_ws;
  p.hT4    = ws;  ws += (size_t)256*64*4;          // 256 KB
  p.YT     = ws;  ws += (size_t)3072*64;           // 768 KB
  p.xiT4   = ws;  ws += (size_t)128*64*4;          // 128 KB
  p.W_r2iT = ws;  ws += (size_t)MM*II;             // 128 KB
  p.memT   = ws;  ws += (size_t)BB*MM*NN;          // 16 MB    (total ~17.3 MB)

  hipMemcpyAsync(p.h,  h0,  (size_t)BB*HH*sizeof(float), hipMemcpyDeviceToDevice, stream);
  hipMemcpyAsync(p.wr, wr0, (size_t)BB*NN*sizeof(float), hipMemcpyDeviceToDevice, stream);
  hipMemcpyAsync(p.ww, ww0, (size_t)BB*NN*sizeof(float), hipMemcpyDeviceToDevice, stream);

  void* args[] = { (void*)&p };
  hipLaunchCooperativeKernel((const void*)ntm_all, dim3(256), dim3(256), args, 0, stream);
}

// Round 5
// 6255.070 us; speedup vs baseline: 1.0174x; 1.0174x over previous
//
#include <hip/hip_runtime.h>
#include <hip/hip_cooperative_groups.h>
#include <math.h>

namespace cg = cooperative_groups;

#define BB 64
#define TT 32
#define II 512
#define HH 1024
#define OO 512
#define NN 1024
#define MM 64
#define EPSF 1e-8f

#define NROWA 3852   // 3072 Whh + 512 Who + 268 gate rows (all dot h, k=1024)
#define NGATE 268

// global layouts:
//  hT4  [k4 0..255][b 0..63][4]
//  xiT4 [k4 0..127][b 0..63][4]
//  YT   [row 0..3071][b]   (Whh·h + bhh)
//  GY   [g 0..267][b]      (activated gate values; s-rows raw)
//  memT [b][m][n]
// LDS per block: WaL[16][1024] (its 16 h-GEMV rows), WbL[12][512] (its 12 gi rows), work[4160]

struct P {
  const float *Wk_r,*bk_r,*Wb_r,*bb_r,*Wg_r,*bg_r,*Ws_r,*bs_r,*Wga_r,*bga_r;
  const float *Wk_w,*bk_w,*Wb_w,*bb_w,*Wg_w,*bg_w,*Ws_w,*bs_w,*Wga_w,*bga_w;
  const float *We,*be,*Wa,*ba,*W_r2i,*b_r2i,*Wih,*bih,*Whh,*bhh,*Who,*bho;
  const float *x, *mem0;
  float *outs, *wr, *ww, *memOut, *h;       // outputs
  float *hT4, *YT, *GY, *xiT4, *W_r2iT, *memT;
};

__device__ __forceinline__ float sigmf(float x){ return 1.f/(1.f+expf(-x)); }
__device__ __forceinline__ float splusf(float x){ return fmaxf(x,0.f) + log1pf(expf(-fabsf(x))); }
__device__ __forceinline__ float4 ld4(const float* p){ return *reinterpret_cast<const float4*>(p); }
__device__ __forceinline__ void st4(float* p, float4 v){ *reinterpret_cast<float4*>(p) = v; }
__device__ __forceinline__ float wredsum(float v){
  #pragma unroll
  for (int o = 32; o; o >>= 1) v += __shfl_xor(v, o);
  return v;
}
__device__ __forceinline__ float wredmax(float v){
  #pragma unroll
  for (int o = 32; o; o >>= 1) v = fmaxf(v, __shfl_xor(v, o));
  return v;
}
// NOTE: a macro with a parameter named `w` breaks on member access `.w`
// (preprocessor substitutes inside `w.w`) — use a real function.
__device__ __forceinline__ float dot4f(float a, float4 wv, float4 vv){
  return fmaf(wv.x, vv.x, fmaf(wv.y, vv.y, fmaf(wv.z, vv.z, fmaf(wv.w, vv.w, a))));
}

// gate row descriptor (g in [0,268))
__device__ const float* gate_src(const P& p, int g, float& bias, int& act) {
  if (g < 140) {
    const int head = (g >= 70);
    const int q = g - head*70;
    if (q < 64)  { bias = (head?p.bk_w:p.bk_r)[q]; act=0; return (head?p.Wk_w:p.Wk_r)+(size_t)q*HH; }
    if (q == 64) { bias = (head?p.bb_w:p.bb_r)[0]; act=1; return head?p.Wb_w:p.Wb_r; }
    if (q == 65) { bias = (head?p.bg_w:p.bg_r)[0]; act=2; return head?p.Wg_w:p.Wg_r; }
    if (q < 69)  { bias = (head?p.bs_w:p.bs_r)[q-66]; act=5; return (head?p.Ws_w:p.Ws_r)+(size_t)(q-66)*HH; }
    bias = (head?p.bga_w:p.bga_r)[0]; act=4; return head?p.Wga_w:p.Wga_r;
  }
  if (g < 204) { const int m=g-140; bias=p.be[m]; act=2; return p.We+(size_t)m*HH; }
  const int m = g-204; bias=p.ba[m]; act=0; return p.Wa+(size_t)m*HH;
}

__device__ void emitA(const P& p, int r, float acc, int t, int lane) {
  if (r < 3072) {
    p.YT[(size_t)r*64 + lane] = acc + p.bhh[r];
  } else if (r < 3584) {
    const int o = r - 3072;
    if (t >= 1) p.outs[((size_t)lane*TT + (t-1))*OO + o] = sigmf(acc + p.bho[o]);
  } else {
    const int g = r - 3584;
    float bias; int act;
    gate_src(p, g, bias, act);
    float v = acc + bias;
    if (act==0) v = tanhf(v);
    else if (act==1) v = splusf(v);
    else if (act==2) v = sigmf(v);
    else if (act==4) v = 1.f + splusf(v);
    p.GY[(size_t)g*64 + lane] = v;
  }
}

// -------- phase A: h-GEMV from LDS weights, lanes=b, 2 rows/wave (waves 0..7) --------
__device__ void phaseA(const P& p, const float* WaL, int t, int blk, int wv, int lane) {
  if (wv >= 8) return;
  const int r0 = blk*16 + wv*2;
  const int r1 = r0 + 1;
  if (r0 >= NROWA) return;
  const float* wlA = WaL + (wv*2)*1024;
  const float* wlB = WaL + (wv*2+1)*1024;
  const float* hp = p.hT4 + lane*4;
  float aA0=0.f, aA1=0.f, aB0=0.f, aB1=0.f;
  #pragma unroll 2
  for (int k4 = 0; k4 < 256; k4 += 2) {
    float4 h0 = ld4(hp + (size_t)k4*256);
    float4 h1 = ld4(hp + (size_t)(k4+1)*256);
    float4 wa0 = ld4(wlA + k4*4);
    float4 wa1 = ld4(wlA + (k4+1)*4);
    float4 wb0 = ld4(wlB + k4*4);
    float4 wb1 = ld4(wlB + (k4+1)*4);
    aA0 = dot4f(aA0, wa0, h0); aA1 = dot4f(aA1, wa1, h1);
    aB0 = dot4f(aB0, wb0, h0); aB1 = dot4f(aB1, wb1, h1);
  }
  emitA(p, r0, aA0 + aA1, t, lane);
  if (r1 < NROWA) emitA(p, r1, aB0 + aB1, t, lane);
}

// -------- per-head addressing, thread-owns-n (n = tid) --------
__device__ void head_addr(const P& p, float* work, int head, float sim, float rown2,
                          int b, int tid, int wv, int lane) {
  float* scal = work+320; float* red = work+336; float* wg_s = work+368;
  float* wdst = work + (head ? 2416 : 1392);
  const float beta=scal[head*4+0], g=scal[head*4+1], gam=scal[head*4+2], kn=scal[head*4+3];
  const float s0=scal[8+head*3+0], s1=scal[8+head*3+1], s2=scal[8+head*3+2];
  float pp = beta * sim / (kn * sqrtf(rown2) + EPSF);
  float mx = wredmax(pp);
  if (lane == 0) red[wv] = mx;
  __syncthreads();
  mx = red[0];
  #pragma unroll
  for (int i = 1; i < 16; ++i) mx = fmaxf(mx, red[i]);
  pp = expf(pp - mx);
  float sm = wredsum(pp);
  if (lane == 0) red[16+wv] = sm;
  __syncthreads();
  sm = 0.f;
  #pragma unroll
  for (int i = 0; i < 16; ++i) sm += red[16+i];
  float* wbuf = (head ? p.ww : p.wr) + (size_t)b*NN;
  float wp = wbuf[tid];
  float wg = g * (pp / sm) + (1.f - g) * wp;
  wg_s[tid] = wg;
  __syncthreads();
  float wt = s0*wg_s[(tid+NN-1)&(NN-1)] + s1*wg + s2*wg_s[(tid+1)&(NN-1)];
  float w = powf(wt + 1e-12f, gam);
  float ps = wredsum(w);
  if (lane == 0) red[wv] = ps;
  __syncthreads();
  ps = 0.f;
  #pragma unroll
  for (int i = 0; i < 16; ++i) ps += red[i];
  w = w / (ps + EPSF);
  wbuf[tid] = w;
  wdst[tid] = w;
  __syncthreads();
}

// -------- phase A2: per-b mem chain (blocks 0..63) --------
__device__ void phaseA2(const P& p, float* work, int t, int b, int tid, int wv, int lane) {
  float* kr_s = work;        float* kw_s = work+64;
  float* e_s  = work+128;    float* a_s  = work+192;
  float* r_s  = work+256;    float* scal = work+320;   // 16
  float* wA   = work+1392;   float* wB   = work+2416;
  // gather activated gates
  if (tid < NGATE) {
    const int g = tid;
    float v = p.GY[(size_t)g*64 + b];
    if (g < 64) kr_s[g] = v;
    else if (g == 64) scal[0] = v;
    else if (g == 65) scal[1] = v;
    else if (g < 69)  scal[8 + g-66] = v;
    else if (g == 69) scal[2] = v;
    else if (g < 134) kw_s[g-70] = v;
    else if (g == 134) scal[4] = v;
    else if (g == 135) scal[5] = v;
    else if (g < 139) scal[11 + g-136] = v;
    else if (g == 139) scal[6] = v;
    else if (g < 204) e_s[g-140] = v;
    else a_s[g-204] = v;
  }
  __syncthreads();
  if (wv == 0) { float v = kr_s[lane]; float q = wredsum(v*v); if (lane==0) scal[3] = sqrtf(q); }
  else if (wv == 1) { float v = kw_s[lane]; float q = wredsum(v*v); if (lane==0) scal[7] = sqrtf(q); }
  else if (wv == 2 && lane < 2) {
    float* sv = &scal[8 + lane*3];
    float s0v=sv[0], s1v=sv[1], s2v=sv[2];
    float mxs = fmaxf(s0v, fmaxf(s1v, s2v));
    float e0=expf(s0v-mxs), e1=expf(s1v-mxs), e2=expf(s2v-mxs);
    float inv = 1.f/(e0+e1+e2);
    sv[0]=e0*inv; sv[1]=e1*inv; sv[2]=e2*inv;
  }
  __syncthreads();
  // sim pass over old mem (thread owns n = tid)
  float* mb = p.memT + (size_t)b*MM*NN;
  float simr=0.f, simw=0.f, qq=0.f;
  #pragma unroll 8
  for (int m = 0; m < MM; ++m) {
    float v = mb[(size_t)m*NN + tid];
    simr = fmaf(kr_s[m], v, simr);
    simw = fmaf(kw_s[m], v, simw);
    qq   = fmaf(v, v, qq);
  }
  head_addr(p, work, 0, simr, qq, b, tid, wv, lane);
  head_addr(p, work, 1, simw, qq, b, tid, wv, lane);
  // read (new wr, old mem) + erase/add (new ww), wave owns 4 m rows
  float4 wAr[4], wBr[4];
  #pragma unroll
  for (int c = 0; c < 4; ++c) { wAr[c] = ld4(&wA[c*256 + lane*4]); wBr[c] = ld4(&wB[c*256 + lane*4]); }
  #pragma unroll
  for (int i = 0; i < 4; ++i) {
    const int m = wv*4 + i;
    const float em = e_s[m], am = a_s[m];
    float* rowp = mb + (size_t)m*NN;
    float racc = 0.f;
    #pragma unroll
    for (int c = 0; c < 4; ++c) {
      float4 v = ld4(rowp + c*256 + lane*4);
      racc = dot4f(racc, wAr[c], v);
      float4 nv;
      nv.x = fmaf(wBr[c].x, fmaf(-em, v.x, am), v.x);
      nv.y = fmaf(wBr[c].y, fmaf(-em, v.y, am), v.y);
      nv.z = fmaf(wBr[c].z, fmaf(-em, v.z, am), v.z);
      nv.w = fmaf(wBr[c].w, fmaf(-em, v.w, am), v.w);
      st4(rowp + c*256 + lane*4, nv);
    }
    racc = wredsum(racc);
    if (lane == 0) r_s[m] = racc;
  }
  __syncthreads();
  // rinxi -> xiT4
  if (tid < II) {
    float acc = p.b_r2i[tid];
    #pragma unroll 8
    for (int m = 0; m < MM; ++m) acc = fmaf(p.W_r2iT[(size_t)m*II + tid], r_s[m], acc);
    float xv = p.x[((size_t)b*TT + t)*II + tid];
    float xi = fmaxf(xv + fmaxf(acc, 0.f), 0.f);
    p.xiT4[((size_t)(tid>>2)*64 + b)*4 + (tid&3)] = xi;
  }
}

// -------- phase B: gi-GEMV from LDS + fused GRU (all blocks) --------
__device__ void phaseB(const P& p, const float* WbL, float* work, int blk, int tid, int wv, int lane) {
  float* gi_s = work;   // 12*64
  if (wv < 6) {
    const int rr0 = wv*2, rr1 = rr0 + 1;
    const int row0 = (rr0>>2)*1024 + blk*4 + (rr0&3);
    const int row1 = (rr1>>2)*1024 + blk*4 + (rr1&3);
    const float* wlA = WbL + rr0*512;
    const float* wlB = WbL + rr1*512;
    const float* xp = p.xiT4 + lane*4;
    float aA0=p.bih[row0], aA1=0.f, aB0=p.bih[row1], aB1=0.f;
    #pragma unroll 2
    for (int k4 = 0; k4 < 128; k4 += 2) {
      float4 x0 = ld4(xp + (size_t)k4*256);
      float4 x1 = ld4(xp + (size_t)(k4+1)*256);
      float4 wa0 = ld4(wlA + k4*4);
      float4 wa1 = ld4(wlA + (k4+1)*4);
      float4 wb0 = ld4(wlB + k4*4);
      float4 wb1 = ld4(wlB + (k4+1)*4);
      aA0 = dot4f(aA0, wa0, x0); aA1 = dot4f(aA1, wa1, x1);
      aB0 = dot4f(aB0, wb0, x0); aB1 = dot4f(aB1, wb1, x1);
    }
    gi_s[rr0*64 + lane] = aA0 + aA1;
    gi_s[rr1*64 + lane] = aB0 + aB1;
  }
  __syncthreads();
  if (tid < 256) {
    const int jl = tid >> 6, b = tid & 63;
    const int j = blk*4 + jl;
    float gir = gi_s[(0*4 + jl)*64 + b];
    float giz = gi_s[(1*4 + jl)*64 + b];
    float gin = gi_s[(2*4 + jl)*64 + b];
    float ghr = p.YT[(size_t)j*64 + b];
    float ghz = p.YT[(size_t)(1024+j)*64 + b];
    float ghn = p.YT[(size_t)(2048+j)*64 + b];
    float hold = p.hT4[((size_t)(j>>2)*64 + b)*4 + (j&3)];
    float rr_ = sigmf(gir + ghr);
    float zz  = sigmf(giz + ghz);
    float nn_ = tanhf(gin + rr_*ghn);
    float hn = (1.f - zz)*nn_ + zz*hold;
    p.h[(size_t)b*HH + j] = hn;
    p.hT4[((size_t)(j>>2)*64 + b)*4 + (j&3)] = hn;
  }
}

// -------- prologue/epilogue mem transposes (blocks 0..63), 16 waves --------
__device__ void memT_build(const P& p, float* tile, int b, int wv, int lane) {
  for (int nt = 0; nt < 16; ++nt) {
    const int n0 = nt*64;
    __syncthreads();
    #pragma unroll
    for (int i = 0; i < 4; ++i) {
      const int nn = wv*4 + i;
      tile[nn*65 + lane] = p.mem0[((size_t)b*NN + n0 + nn)*MM + lane];
    }
    __syncthreads();
    #pragma unroll
    for (int i = 0; i < 4; ++i) {
      const int m = wv*4 + i;
      p.memT[((size_t)b*MM + m)*NN + n0 + lane] = tile[lane*65 + m];
    }
  }
}

__device__ void memT_out(const P& p, float* tile, int b, int wv, int lane) {
  for (int nt = 0; nt < 16; ++nt) {
    const int n0 = nt*64;
    __syncthreads();
    #pragma unroll
    for (int i = 0; i < 4; ++i) {
      const int m = wv*4 + i;
      tile[lane*65 + m] = p.memT[((size_t)b*MM + m)*NN + n0 + lane];
    }
    __syncthreads();
    #pragma unroll
    for (int i = 0; i < 4; ++i) {
      const int nn = wv*4 + i;
      p.memOut[((size_t)b*NN + n0 + nn)*MM + lane] = tile[nn*65 + lane];
    }
  }
}

// ---------------- single persistent cooperative kernel ----------------
__global__ __launch_bounds__(1024, 4) void ntm_all(P p) {
  __shared__ float smem[26688];          // 104.25 KB (gfx950 LDS = 160 KB)
  float* WaL  = smem;                    // 16*1024
  float* WbL  = smem + 16384;            // 12*512
  float* work = smem + 22528;            // 4160
  cg::grid_group grid = cg::this_grid();
  const int blk = blockIdx.x, tid = threadIdx.x;
  const int wv = tid >> 6, lane = tid & 63;

  // ---- prologue: LDS weight residency + transposed state builds ----
  {
    const int ra = blk*16 + wv;
    if (ra < NROWA) {
      float bias; int act;
      const float* src = (ra < 3072) ? p.Whh + (size_t)ra*HH
                       : (ra < 3584) ? p.Who + (size_t)(ra-3072)*HH
                       : gate_src(p, ra-3584, bias, act);
      float* wl = WaL + wv*1024;
      #pragma unroll
      for (int c = 0; c < 4; ++c) st4(wl + c*256 + lane*4, ld4(src + c*256 + lane*4));
    }
    if (wv < 6) {
      #pragma unroll
      for (int q = 0; q < 2; ++q) {
        const int rr = wv*2 + q;
        const int row = (rr>>2)*1024 + blk*4 + (rr&3);
        float* wl = WbL + rr*512;
        const float* src = p.Wih + (size_t)row*II;
        #pragma unroll
        for (int c = 0; c < 2; ++c) st4(wl + c*256 + lane*4, ld4(src + c*256 + lane*4));
      }
    }
    if (blk < 64) {
      memT_build(p, work, blk, wv, lane);
    } else if (blk < 128) {
      const int m = blk - 64;
      if (tid < II) p.W_r2iT[(size_t)m*II + tid] = p.W_r2i[(size_t)tid*MM + m];
    } else if (blk < 192) {
      const int b = blk - 128;
      if (tid < 256) {
        float4 v = ld4(p.h + (size_t)b*HH + tid*4);
        st4(p.hT4 + ((size_t)tid*64 + b)*4, v);
      }
    }
  }
  grid.sync();

  // ---- time loop: 3 grid syncs / step ----
  for (int t = 0; t < TT; ++t) {
    phaseA(p, WaL, t, blk, wv, lane);
    grid.sync();
    if (blk < 64) phaseA2(p, work, t, blk, tid, wv, lane);
    grid.sync();
    phaseB(p, WbL, work, blk, tid, wv, lane);
    grid.sync();
  }

  // ---- epilogue: out[T-1] (Who blocks 192..223) + mem back-transpose ----
  if (blk >= 192 && blk < 224) phaseA(p, WaL, TT, blk, wv, lane);
  else if (blk < 64) memT_out(p, work, blk, wv, lane);
}

extern "C" void kernel_launch(void* const* d_in, const int* in_sizes, int n_in,
                              void* d_out, int out_size, void* d_ws, size_t ws_size,
                              hipStream_t stream) {
  const float* x    = (const float*)d_in[0];
  const float* h0   = (const float*)d_in[1];
  const float* wr0  = (const float*)d_in[2];
  const float* ww0  = (const float*)d_in[3];
  const float* mem0 = (const float*)d_in[4];
  P p;
  int i = 5;
  p.Wk_r  = (const float*)d_in[i++]; p.bk_r  = (const float*)d_in[i++];
  p.Wb_r  = (const float*)d_in[i++]; p.bb_r  = (const float*)d_in[i++];
  p.Wg_r  = (const float*)d_in[i++]; p.bg_r  = (const float*)d_in[i++];
  p.Ws_r  = (const float*)d_in[i++]; p.bs_r  = (const float*)d_in[i++];
  p.Wga_r = (const float*)d_in[i++]; p.bga_r = (const float*)d_in[i++];
  p.Wk_w  = (const float*)d_in[i++]; p.bk_w  = (const float*)d_in[i++];
  p.Wb_w  = (const float*)d_in[i++]; p.bb_w  = (const float*)d_in[i++];
  p.Wg_w  = (const float*)d_in[i++]; p.bg_w  = (const float*)d_in[i++];
  p.Ws_w  = (const float*)d_in[i++]; p.bs_w  = (const float*)d_in[i++];
  p.Wga_w = (const float*)d_in[i++]; p.bga_w = (const float*)d_in[i++];
  p.We    = (const float*)d_in[i++]; p.be    = (const float*)d_in[i++];
  p.Wa    = (const float*)d_in[i++]; p.ba    = (const float*)d_in[i++];
  p.W_r2i = (const float*)d_in[i++]; p.b_r2i = (const float*)d_in[i++];
  p.Wih   = (const float*)d_in[i++]; p.bih   = (const float*)d_in[i++];
  p.Whh   = (const float*)d_in[i++]; p.bhh   = (const float*)d_in[i++];
  p.Who   = (const float*)d_in[i++]; p.bho   = (const float*)d_in[i++];
  p.x = x; p.mem0 = mem0;

  float* out = (float*)d_out;
  p.outs   = out;                                  // (B,T,O)
  p.h      = out + (size_t)BB*TT*OO;               // (B,H) final h
  p.wr     = p.h + (size_t)BB*HH;                  // (B,N)
  p.ww     = p.wr + (size_t)BB*NN;                 // (B,N)
  p.memOut = p.ww + (size_t)BB*NN;                 // (B,N,M)

  float* ws = (float*)d_ws;
  p.hT4    = ws;  ws += (size_t)256*64*4;          // 256 KB
  p.YT     = ws;  ws += (size_t)3072*64;           // 768 KB
  p.GY     = ws;  ws += (size_t)NGATE*64;          // 67 KB
  p.xiT4   = ws;  ws += (size_t)128*64*4;          // 128 KB
  p.W_r2iT = ws;  ws += (size_t)MM*II;             // 128 KB
  p.memT   = ws;  ws += (size_t)BB*MM*NN;          // 16 MB   (total ~17.35 MB)

  hipMemcpyAsync(p.h,  h0,  (size_t)BB*HH*sizeof(float), hipMemcpyDeviceToDevice, stream);
  hipMemcpyAsync(p.wr, wr0, (size_t)BB*NN*sizeof(float), hipMemcpyDeviceToDevice, stream);
  hipMemcpyAsync(p.ww, ww0, (size_t)BB*NN*sizeof(float), hipMemcpyDeviceToDevice, stream);

  void* args[] = { (void*)&p };
  hipLaunchCooperativeKernel((const void*)ntm_all, dim3(256), dim3(1024), args, 0, stream);
}